// Round 7
// baseline (2759.673 us; speedup 1.0000x reference)
//
#include <hip/hip_runtime.h>
#include <math.h>

#define NHEADS 6
#define DMODEL 384
#define TMAXT  577
#define NMAXT  576
#define BATCH  8
#define LAYERS 12

typedef __attribute__((ext_vector_type(8))) short bf16x8v;
typedef __attribute__((ext_vector_type(4))) float f32x4v;

// ---------------- workspace layout (float indices) ----------------
#define XSZ      (8ull*577*384)            // 1,772,544
#define X0_OFF   0ull
#define X1_OFF   (X0_OFF + XSZ)
#define XN_OFF   (X1_OFF + XSZ)            // xn split planes: 2 x XSZ ushort
#define QKV_OFF  (XN_OFF + XSZ)
#define QKV_SZ   (8ull*577*1152)           // elements per plane
#define AO_OFF   (QKV_OFF + QKV_SZ)        // qkv split planes = QKV_SZ floats total
#define HBELEM   (8ull*577*1536)
#define RAWH_OFF (AO_OFF + XSZ)
#define RAWH_SZ  (8ull*6*576)
#define ENT_OFF  (RAWH_OFF + RAWH_SZ)
#define PM_OFF   (ENT_OFF + 64)
#define XF_OFF   (PM_OFF + 64)
#define KEEP_OFF (XF_OFF + 8*384)
#define T_OFF    (KEEP_OFF + 640)          // T slot 0
#define TN_OFF   (T_OFF + 16)              // T slot 1
#define WSPL_OFF (TN_OFF + 16)

// weight split sub-offsets (ushort units inside WSPL)
#define W_QKV   0ull
#define W_PROJ  884736ull
#define W_FC1   1179648ull
#define W_FC2   2359296ull
#define W_PATCH 3538944ull                 // 768*384*2 = 589,824 ushorts

// ---------------- bf16 split helpers ----------------
__device__ inline unsigned short rne_bf16(float f) {
    unsigned int u = __float_as_uint(f);
    u += 0x7FFFu + ((u >> 16) & 1u);
    return (unsigned short)(u >> 16);
}
__device__ inline float bf16_to_f(unsigned short h) {
    return __uint_as_float(((unsigned int)h) << 16);
}
__device__ inline void split_bf16(float x, unsigned short& h, unsigned short& l) {
    h = rne_bf16(x);
    l = rne_bf16(x - bf16_to_f(h));
}

// ---------------- prologue: cls row + pos, init T slot 0 ----------------
__global__ __launch_bounds__(128) void prologue_kernel(const float* __restrict__ cls_tok,
                                                       const float* __restrict__ pos,
                                                       float* __restrict__ x0,
                                                       int* __restrict__ dT0)
{
    int b = blockIdx.x;
    for (int d = threadIdx.x; d < 384; d += 128)
        x0[(size_t)b*577*384 + d] = cls_tok[d] + pos[d];
    if (b == 0 && threadIdx.x == 0) *dT0 = 577;
}

// ---------------- generic split+transpose: W[K][N] fp32 -> [N][K] hi/lo bf16 ----------------
__global__ __launch_bounds__(256) void psplit_kernel(const float* __restrict__ W,
                                                     unsigned short* __restrict__ dst,
                                                     int K, int N)
{
    int ktiles = K >> 5, ntiles = N >> 5;
    int tid = blockIdx.x;
    if (tid >= ktiles * ntiles) return;
    int tk = tid % ktiles, tn = tid / ktiles;
    int k0 = tk << 5, n0 = tn << 5;
    __shared__ unsigned short Th[32][34];
    __shared__ unsigned short Tl[32][34];
    int t = threadIdx.x;
    {
        int row = t >> 3, c4 = (t & 7) << 2;
        float4 wv = *(const float4*)(W + (size_t)(k0 + row) * N + n0 + c4);
        unsigned short h, l;
        split_bf16(wv.x, h, l); Th[c4+0][row] = h; Tl[c4+0][row] = l;
        split_bf16(wv.y, h, l); Th[c4+1][row] = h; Tl[c4+1][row] = l;
        split_bf16(wv.z, h, l); Th[c4+2][row] = h; Tl[c4+2][row] = l;
        split_bf16(wv.w, h, l); Th[c4+3][row] = h; Tl[c4+3][row] = l;
    }
    __syncthreads();
    {
        int n = t >> 3, k4 = (t & 7) << 2;
        unsigned short* dh = dst + (size_t)(n0 + n) * K + k0 + k4;
        unsigned short* dl = dh + (size_t)K * N;
        *(ushort4*)dh = make_ushort4(Th[n][k4], Th[n][k4+1], Th[n][k4+2], Th[n][k4+3]);
        *(ushort4*)dl = make_ushort4(Tl[n][k4], Tl[n][k4+1], Tl[n][k4+2], Tl[n][k4+3]);
    }
}

// ---------------- per-layer weight split (4 matrices) ----------------
__global__ __launch_bounds__(256) void wsplit_kernel(const float* __restrict__ qkvw,
                                                     const float* __restrict__ projw,
                                                     const float* __restrict__ fc1w,
                                                     const float* __restrict__ fc2w,
                                                     unsigned short* __restrict__ wspl)
{
    int mat = blockIdx.y;
    const float* W; int K, N; size_t off;
    if (mat == 0)      { W = qkvw; K = 384;  N = 1152; off = W_QKV; }
    else if (mat == 1) { W = projw; K = 384; N = 384;  off = W_PROJ; }
    else if (mat == 2) { W = fc1w; K = 384;  N = 1536; off = W_FC1; }
    else               { W = fc2w; K = 1536; N = 384;  off = W_FC2; }
    int ktiles = K >> 5, ntiles = N >> 5;
    int tid = blockIdx.x;
    if (tid >= ktiles * ntiles) return;
    int tk = tid % ktiles, tn = tid / ktiles;
    int k0 = tk << 5, n0 = tn << 5;
    __shared__ unsigned short Th[32][34];
    __shared__ unsigned short Tl[32][34];
    int t = threadIdx.x;
    {
        int row = t >> 3, c4 = (t & 7) << 2;
        float4 wv = *(const float4*)(W + (size_t)(k0 + row) * N + n0 + c4);
        unsigned short h, l;
        split_bf16(wv.x, h, l); Th[c4+0][row] = h; Tl[c4+0][row] = l;
        split_bf16(wv.y, h, l); Th[c4+1][row] = h; Tl[c4+1][row] = l;
        split_bf16(wv.z, h, l); Th[c4+2][row] = h; Tl[c4+2][row] = l;
        split_bf16(wv.w, h, l); Th[c4+3][row] = h; Tl[c4+3][row] = l;
    }
    __syncthreads();
    {
        int n = t >> 3, k4 = (t & 7) << 2;
        unsigned short* dh = wspl + off + (size_t)(n0 + n) * K + k0 + k4;
        unsigned short* dl = dh + (size_t)K * N;
        *(ushort4*)dh = make_ushort4(Th[n][k4], Th[n][k4+1], Th[n][k4+2], Th[n][k4+3]);
        *(ushort4*)dl = make_ushort4(Tl[n][k4], Tl[n][k4+1], Tl[n][k4+2], Tl[n][k4+3]);
    }
}

// ---------------- patch embed: bf16x3 MFMA, 64x64 tile ----------------
__global__ __launch_bounds__(256, 4) void patch_mfma_kernel(const float* __restrict__ x,
                                                            const unsigned short* __restrict__ Wt,
                                                            const float* __restrict__ pb,
                                                            const float* __restrict__ pos,
                                                            float* __restrict__ x0)
{
    const int K = 768, N = 384, M = 4608;
    int m0 = blockIdx.y * 64;
    int n0 = blockIdx.x * 64;

    __shared__ unsigned short As[2][64][40];
    __shared__ unsigned short Bs[2][64][40];

    int t = threadIdx.x;
    int lane = t & 63, w = t >> 6;
    int wr = w >> 1, wc = w & 1;
    int quad = lane >> 4, l16 = lane & 15;

    f32x4v acc[2][2];
#pragma unroll
    for (int i = 0; i < 2; i++)
#pragma unroll
        for (int j = 0; j < 2; j++) acc[i][j] = (f32x4v){0.f, 0.f, 0.f, 0.f};

    int arow = t >> 2, ak8 = (t & 3) * 8;
    int garow = m0 + arow;
    int ab = garow / 576, att = garow % 576;
    int g1 = att / 24, g2 = att % 24;
    const float* xr = x + ((size_t)(ab*3)*384 + g1*16)*384 + g2*16;

    int bn = t >> 2, bk8 = (t & 3) * 8;
    const unsigned short* Bh = Wt + (size_t)(n0 + bn) * K + bk8;
    const unsigned short* Bl = Bh + (size_t)K * N;

    for (int k0 = 0; k0 < K; k0 += 32) {
        int k = k0 + ak8;
        int c = k >> 8, rr = k & 255, p1 = rr >> 4, p2 = rr & 15;
        const float* src = xr + ((size_t)c*384 + p1)*384 + p2;
        float4 f0 = *(const float4*)(src);
        float4 f1 = *(const float4*)(src + 4);
        float f[8] = {f0.x, f0.y, f0.z, f0.w, f1.x, f1.y, f1.z, f1.w};
        unsigned short ah[8], al[8];
#pragma unroll
        for (int j = 0; j < 8; j++) split_bf16(f[j], ah[j], al[j]);
        uint4 vbh = *(const uint4*)(Bh + k0);
        uint4 vbl = *(const uint4*)(Bl + k0);
        __syncthreads();
        *(uint4*)&As[0][arow][ak8] = *(uint4*)ah;
        *(uint4*)&As[1][arow][ak8] = *(uint4*)al;
        *(uint4*)&Bs[0][bn][bk8] = vbh;
        *(uint4*)&Bs[1][bn][bk8] = vbl;
        __syncthreads();

        bf16x8v afh[2], afl[2], bfh[2], bfl[2];
#pragma unroll
        for (int rb = 0; rb < 2; rb++) {
            int r = wr * 32 + rb * 16 + l16;
            afh[rb] = *(const bf16x8v*)&As[0][r][quad * 8];
            afl[rb] = *(const bf16x8v*)&As[1][r][quad * 8];
        }
#pragma unroll
        for (int cb = 0; cb < 2; cb++) {
            int cc = wc * 32 + cb * 16 + l16;
            bfh[cb] = *(const bf16x8v*)&Bs[0][cc][quad * 8];
            bfl[cb] = *(const bf16x8v*)&Bs[1][cc][quad * 8];
        }
#pragma unroll
        for (int rb = 0; rb < 2; rb++)
#pragma unroll
            for (int cb = 0; cb < 2; cb++) {
                acc[rb][cb] = __builtin_amdgcn_mfma_f32_16x16x32_bf16(afl[rb], bfh[cb], acc[rb][cb], 0, 0, 0);
                acc[rb][cb] = __builtin_amdgcn_mfma_f32_16x16x32_bf16(afh[rb], bfl[cb], acc[rb][cb], 0, 0, 0);
                acc[rb][cb] = __builtin_amdgcn_mfma_f32_16x16x32_bf16(afh[rb], bfh[cb], acc[rb][cb], 0, 0, 0);
            }
    }

#pragma unroll
    for (int rb = 0; rb < 2; rb++) {
#pragma unroll
        for (int reg = 0; reg < 4; reg++) {
            int r = m0 + wr * 32 + rb * 16 + quad * 4 + reg;
            if (r >= M) continue;
            int bb = r / 576, ttt = r % 576;
#pragma unroll
            for (int cb = 0; cb < 2; cb++) {
                int cc = n0 + wc * 32 + cb * 16 + l16;
                float v = acc[rb][cb][reg] + pb[cc] + pos[(size_t)(1 + ttt)*384 + cc];
                x0[(size_t)(bb*577 + 1 + ttt)*384 + cc] = v;
            }
        }
    }
}

// ---------------- LayerNorm -> split bf16 planes ----------------
__global__ __launch_bounds__(256) void ln_kernel(const float* __restrict__ xin,
                                                 const float* __restrict__ sc,
                                                 const float* __restrict__ bi,
                                                 unsigned short* __restrict__ yhi,
                                                 unsigned short* __restrict__ ylo,
                                                 const int* __restrict__ dT)
{
    int T = *dT;
    int M = 8 * T;
    int r = blockIdx.x * 4 + (threadIdx.x >> 6);
    if (r >= M) return;
    int lane = threadIdx.x & 63;
    const float* xr = xin + (size_t)r * 384;
    float v[6];
#pragma unroll
    for (int i = 0; i < 6; i++) v[i] = xr[lane + 64*i];
    float s = v[0]+v[1]+v[2]+v[3]+v[4]+v[5];
#pragma unroll
    for (int off = 32; off; off >>= 1) s += __shfl_xor(s, off, 64);
    float mean = s * (1.0f/384.0f);
    float q = 0.f;
#pragma unroll
    for (int i = 0; i < 6; i++) { float d = v[i]-mean; q += d*d; }
#pragma unroll
    for (int off = 32; off; off >>= 1) q += __shfl_xor(q, off, 64);
    float rstd = 1.0f / sqrtf(q * (1.0f/384.0f) + 1e-5f);
#pragma unroll
    for (int i = 0; i < 6; i++) {
        int d = lane + 64*i;
        float y = (v[i]-mean) * rstd * sc[d] + bi[d];
        unsigned short h, l;
        split_bf16(y, h, l);
        yhi[(size_t)r*384 + d] = h;
        ylo[(size_t)r*384 + d] = l;
    }
}

// ---------------- bf16x3 MFMA GEMM, 64x128 tile, split-bf16 out (+optional gelu) ----------------
template<bool GELU>
__global__ __launch_bounds__(256, 3) void gemm3_kernel(const unsigned short* __restrict__ Ahi,
                                                       const unsigned short* __restrict__ Alo,
                                                       const unsigned short* __restrict__ Wt,
                                                       const float* __restrict__ bias,
                                                       unsigned short* __restrict__ Chi,
                                                       unsigned short* __restrict__ Clo,
                                                       int K, int N,
                                                       const int* __restrict__ dT)
{
    int T = *dT; int M = 8 * T;
    int m0 = blockIdx.y * 64;
    if (m0 >= M) return;
    int n0 = blockIdx.x * 128;

    __shared__ unsigned short As[2][64][40];
    __shared__ unsigned short Bs[2][128][40];

    int t = threadIdx.x;
    int lane = t & 63, w = t >> 6;
    int wr = w >> 1, wc = w & 1;
    int quad = lane >> 4, l16 = lane & 15;

    f32x4v acc[2][4];
#pragma unroll
    for (int i = 0; i < 2; i++)
#pragma unroll
        for (int j = 0; j < 4; j++) acc[i][j] = (f32x4v){0.f, 0.f, 0.f, 0.f};

    int arow = t >> 2, ak = (t & 3) * 8;
    int ag = m0 + arow; if (ag > M - 1) ag = M - 1;
    const unsigned short* Ah = Ahi + (size_t)ag * K + ak;
    const unsigned short* Al = Alo + (size_t)ag * K + ak;

    int bn = t >> 1, bk = (t & 1) * 16;
    const unsigned short* Bh = Wt + (size_t)(n0 + bn) * K + bk;
    const unsigned short* Bl = Bh + (size_t)K * N;

    for (int k0 = 0; k0 < K; k0 += 32) {
        uint4 vah  = *(const uint4*)(Ah + k0);
        uint4 val  = *(const uint4*)(Al + k0);
        uint4 vbh0 = *(const uint4*)(Bh + k0);
        uint4 vbh1 = *(const uint4*)(Bh + k0 + 8);
        uint4 vbl0 = *(const uint4*)(Bl + k0);
        uint4 vbl1 = *(const uint4*)(Bl + k0 + 8);
        __syncthreads();
        *(uint4*)&As[0][arow][ak] = vah;
        *(uint4*)&As[1][arow][ak] = val;
        *(uint4*)&Bs[0][bn][bk]     = vbh0;
        *(uint4*)&Bs[0][bn][bk + 8] = vbh1;
        *(uint4*)&Bs[1][bn][bk]     = vbl0;
        *(uint4*)&Bs[1][bn][bk + 8] = vbl1;
        __syncthreads();

        bf16x8v afh[2], afl[2], bfh[4], bfl[4];
#pragma unroll
        for (int rb = 0; rb < 2; rb++) {
            int r = wr * 32 + rb * 16 + l16;
            afh[rb] = *(const bf16x8v*)&As[0][r][quad * 8];
            afl[rb] = *(const bf16x8v*)&As[1][r][quad * 8];
        }
#pragma unroll
        for (int cb = 0; cb < 4; cb++) {
            int c = wc * 64 + cb * 16 + l16;
            bfh[cb] = *(const bf16x8v*)&Bs[0][c][quad * 8];
            bfl[cb] = *(const bf16x8v*)&Bs[1][c][quad * 8];
        }
#pragma unroll
        for (int rb = 0; rb < 2; rb++)
#pragma unroll
            for (int cb = 0; cb < 4; cb++) {
                acc[rb][cb] = __builtin_amdgcn_mfma_f32_16x16x32_bf16(afl[rb], bfh[cb], acc[rb][cb], 0, 0, 0);
                acc[rb][cb] = __builtin_amdgcn_mfma_f32_16x16x32_bf16(afh[rb], bfl[cb], acc[rb][cb], 0, 0, 0);
                acc[rb][cb] = __builtin_amdgcn_mfma_f32_16x16x32_bf16(afh[rb], bfh[cb], acc[rb][cb], 0, 0, 0);
            }
    }

#pragma unroll
    for (int rb = 0; rb < 2; rb++) {
#pragma unroll
        for (int reg = 0; reg < 4; reg++) {
            int r = m0 + wr * 32 + rb * 16 + quad * 4 + reg;
            if (r >= M) continue;
#pragma unroll
            for (int cb = 0; cb < 4; cb++) {
                int c = n0 + wc * 64 + cb * 16 + l16;
                float v = acc[rb][cb][reg] + bias[c];
                if (GELU) v = 0.5f * v * (1.0f + erff(v * 0.70710678118654752440f));
                unsigned short h, l;
                split_bf16(v, h, l);
                Chi[(size_t)r * N + c] = h;
                Clo[(size_t)r * N + c] = l;
            }
        }
    }
}

// ---------------- bf16x3 MFMA GEMM, 64x64 tile, +resid, fp32 out (N=384 GEMMs) ----------------
__global__ __launch_bounds__(256, 4) void gemm64_kernel(const unsigned short* __restrict__ Ahi,
                                                        const unsigned short* __restrict__ Alo,
                                                        const unsigned short* __restrict__ Wt,
                                                        const float* __restrict__ bias,
                                                        const float* __restrict__ resid,
                                                        float* __restrict__ Cf,
                                                        int K, int N,
                                                        const int* __restrict__ dT)
{
    int T = *dT; int M = 8 * T;
    int m0 = blockIdx.y * 64;
    if (m0 >= M) return;
    int n0 = blockIdx.x * 64;

    __shared__ unsigned short As[2][64][40];
    __shared__ unsigned short Bs[2][64][40];

    int t = threadIdx.x;
    int lane = t & 63, w = t >> 6;
    int wr = w >> 1, wc = w & 1;
    int quad = lane >> 4, l16 = lane & 15;

    f32x4v acc[2][2];
#pragma unroll
    for (int i = 0; i < 2; i++)
#pragma unroll
        for (int j = 0; j < 2; j++) acc[i][j] = (f32x4v){0.f, 0.f, 0.f, 0.f};

    int arow = t >> 2, ak = (t & 3) * 8;
    int ag = m0 + arow; if (ag > M - 1) ag = M - 1;
    const unsigned short* Ah = Ahi + (size_t)ag * K + ak;
    const unsigned short* Al = Alo + (size_t)ag * K + ak;

    int bn = t >> 2, bk = (t & 3) * 8;
    const unsigned short* Bh = Wt + (size_t)(n0 + bn) * K + bk;
    const unsigned short* Bl = Bh + (size_t)K * N;

    for (int k0 = 0; k0 < K; k0 += 32) {
        uint4 vah = *(const uint4*)(Ah + k0);
        uint4 val = *(const uint4*)(Al + k0);
        uint4 vbh = *(const uint4*)(Bh + k0);
        uint4 vbl = *(const uint4*)(Bl + k0);
        __syncthreads();
        *(uint4*)&As[0][arow][ak] = vah;
        *(uint4*)&As[1][arow][ak] = val;
        *(uint4*)&Bs[0][bn][bk] = vbh;
        *(uint4*)&Bs[1][bn][bk] = vbl;
        __syncthreads();

        bf16x8v afh[2], afl[2], bfh[2], bfl[2];
#pragma unroll
        for (int rb = 0; rb < 2; rb++) {
            int r = wr * 32 + rb * 16 + l16;
            afh[rb] = *(const bf16x8v*)&As[0][r][quad * 8];
            afl[rb] = *(const bf16x8v*)&As[1][r][quad * 8];
        }
#pragma unroll
        for (int cb = 0; cb < 2; cb++) {
            int c = wc * 32 + cb * 16 + l16;
            bfh[cb] = *(const bf16x8v*)&Bs[0][c][quad * 8];
            bfl[cb] = *(const bf16x8v*)&Bs[1][c][quad * 8];
        }
#pragma unroll
        for (int rb = 0; rb < 2; rb++)
#pragma unroll
            for (int cb = 0; cb < 2; cb++) {
                acc[rb][cb] = __builtin_amdgcn_mfma_f32_16x16x32_bf16(afl[rb], bfh[cb], acc[rb][cb], 0, 0, 0);
                acc[rb][cb] = __builtin_amdgcn_mfma_f32_16x16x32_bf16(afh[rb], bfl[cb], acc[rb][cb], 0, 0, 0);
                acc[rb][cb] = __builtin_amdgcn_mfma_f32_16x16x32_bf16(afh[rb], bfh[cb], acc[rb][cb], 0, 0, 0);
            }
    }

#pragma unroll
    for (int rb = 0; rb < 2; rb++) {
#pragma unroll
        for (int reg = 0; reg < 4; reg++) {
            int r = m0 + wr * 32 + rb * 16 + quad * 4 + reg;
            if (r >= M) continue;
#pragma unroll
            for (int cb = 0; cb < 2; cb++) {
                int c = n0 + wc * 32 + cb * 16 + l16;
                float v = acc[rb][cb][reg] + bias[c] + resid[(size_t)r * N + c];
                Cf[(size_t)r * N + c] = v;
            }
        }
    }
}

// ---------------- flash attention v4: pre-split qkv planes, MFMA QK^T/PV ----------------
__global__ __launch_bounds__(256, 3) void attn_kernel(const unsigned short* __restrict__ qh,
                                                      const unsigned short* __restrict__ ql,
                                                      unsigned short* __restrict__ out_hi,
                                                      unsigned short* __restrict__ out_lo,
                                                      const int* __restrict__ dT)
{
    int T = *dT;
    int q0 = blockIdx.x * 64;
    if (q0 >= T) return;
    int bh = blockIdx.y;
    int b = bh / NHEADS, h = bh % NHEADS;

    __shared__ unsigned short Ks[2][64][72];   // K tile [tok][d]; later P [q][ktok]
    __shared__ unsigned short Vt[2][64][72];   // V^T tile [d][tok]
    __shared__ float Ss[64][66];
    __shared__ float m_s[64], l_s[64], al_s[64];

    int t = threadIdx.x;
    int lane = t & 63, w = t >> 6;
    int l16 = lane & 15, quad = lane >> 4;

    const bf16x8v zf = (bf16x8v){0,0,0,0,0,0,0,0};
    bf16x8v qf[2][2];   // [kstep][hi/lo]
    {
        int gq = q0 + w * 16 + l16;
        bool valid = gq < T;
        size_t base = (size_t)(b * T + (valid ? gq : 0)) * 1152 + h * 64;
#pragma unroll
        for (int ks = 0; ks < 2; ks++) {
            int off = ks * 32 + quad * 8;
            qf[ks][0] = valid ? *(const bf16x8v*)(qh + base + off) : zf;
            qf[ks][1] = valid ? *(const bf16x8v*)(ql + base + off) : zf;
        }
    }
    if (t < 64) { m_s[t] = -INFINITY; l_s[t] = 0.f; }

    f32x4v oacc[4];
#pragma unroll
    for (int cb = 0; cb < 4; cb++) oacc[cb] = (f32x4v){0.f, 0.f, 0.f, 0.f};

    int ntiles = (T + 63) >> 6;
    for (int kt = 0; kt < ntiles; kt++) {
        int kbase = kt * 64;
        __syncthreads();

        // stage K direct (pre-split), V transposed
        {
            int gk = kbase + lane;
            int sd0 = w * 16;
            bool valid = gk < T;
            size_t base = (size_t)(b * T + (valid ? gk : 0)) * 1152 + 384 + h * 64 + sd0;
            const uint4 z4 = make_uint4(0,0,0,0);
            uint4 kh0 = valid ? *(const uint4*)(qh + base)     : z4;
            uint4 kh1 = valid ? *(const uint4*)(qh + base + 8) : z4;
            uint4 kl0 = valid ? *(const uint4*)(ql + base)     : z4;
            uint4 kl1 = valid ? *(const uint4*)(ql + base + 8) : z4;
            *(uint4*)&Ks[0][lane][sd0]     = kh0;
            *(uint4*)&Ks[0][lane][sd0 + 8] = kh1;
            *(uint4*)&Ks[1][lane][sd0]     = kl0;
            *(uint4*)&Ks[1][lane][sd0 + 8] = kl1;
            uint4 vh0 = valid ? *(const uint4*)(qh + base + 384)     : z4;
            uint4 vh1 = valid ? *(const uint4*)(qh + base + 384 + 8) : z4;
            uint4 vl0 = valid ? *(const uint4*)(ql + base + 384)     : z4;
            uint4 vl1 = valid ? *(const uint4*)(ql + base + 384 + 8) : z4;
            unsigned short th[16], tl[16];
            *(uint4*)&th[0] = vh0; *(uint4*)&th[8] = vh1;
            *(uint4*)&tl[0] = vl0; *(uint4*)&tl[8] = vl1;
#pragma unroll
            for (int i = 0; i < 16; i++) {
                Vt[0][sd0 + i][lane] = th[i];
                Vt[1][sd0 + i][lane] = tl[i];
            }
        }
        __syncthreads();

        // S = Q K^T
#pragma unroll
        for (int cb = 0; cb < 4; cb++) {
            f32x4v sacc = (f32x4v){0.f, 0.f, 0.f, 0.f};
#pragma unroll
            for (int ks = 0; ks < 2; ks++) {
                bf16x8v bhi = *(const bf16x8v*)&Ks[0][cb*16 + l16][ks*32 + quad*8];
                bf16x8v blo = *(const bf16x8v*)&Ks[1][cb*16 + l16][ks*32 + quad*8];
                sacc = __builtin_amdgcn_mfma_f32_16x16x32_bf16(qf[ks][1], bhi, sacc, 0, 0, 0);
                sacc = __builtin_amdgcn_mfma_f32_16x16x32_bf16(qf[ks][0], blo, sacc, 0, 0, 0);
                sacc = __builtin_amdgcn_mfma_f32_16x16x32_bf16(qf[ks][0], bhi, sacc, 0, 0, 0);
            }
            int col = cb*16 + l16;
            int gk = kbase + col;
#pragma unroll
            for (int reg = 0; reg < 4; reg++)
                Ss[w*16 + quad*4 + reg][col] = (gk < T) ? sacc[reg]*0.125f : -INFINITY;
        }
        __syncthreads();

        // online softmax; P split overwrites Ks
        {
            int rr = t >> 2, sub = t & 3;
            float mx = -INFINITY;
#pragma unroll
            for (int kk = 0; kk < 16; kk++) mx = fmaxf(mx, Ss[rr][sub*16 + kk]);
            mx = fmaxf(mx, __shfl_xor(mx, 1, 64));
            mx = fmaxf(mx, __shfl_xor(mx, 2, 64));
            float mold = m_s[rr];
            float newm = fmaxf(mold, mx);
            float ps = 0.f;
#pragma unroll
            for (int kk = 0; kk < 16; kk++) {
                float p = __expf(Ss[rr][sub*16 + kk] - newm);
                unsigned short hh, ll;
                split_bf16(p, hh, ll);
                Ks[0][rr][sub*16 + kk] = hh;
                Ks[1][rr][sub*16 + kk] = ll;
                ps += p;
            }
            ps += __shfl_xor(ps, 1, 64);
            ps += __shfl_xor(ps, 2, 64);
            if (sub == 0) {
                float alpha = __expf(mold - newm);
                l_s[rr] = l_s[rr]*alpha + ps;
                m_s[rr] = newm;
                al_s[rr] = alpha;
            }
        }
        __syncthreads();

        // O = alpha*O + P V
#pragma unroll
        for (int reg = 0; reg < 4; reg++) {
            float a = al_s[w*16 + quad*4 + reg];
#pragma unroll
            for (int cb = 0; cb < 4; cb++) oacc[cb][reg] *= a;
        }
#pragma unroll
        for (int ks = 0; ks < 2; ks++) {
            bf16x8v phi = *(const bf16x8v*)&Ks[0][w*16 + l16][ks*32 + quad*8];
            bf16x8v plo = *(const bf16x8v*)&Ks[1][w*16 + l16][ks*32 + quad*8];
#pragma unroll
            for (int cb = 0; cb < 4; cb++) {
                bf16x8v vhi = *(const bf16x8v*)&Vt[0][cb*16 + l16][ks*32 + quad*8];
                bf16x8v vlo = *(const bf16x8v*)&Vt[1][cb*16 + l16][ks*32 + quad*8];
                oacc[cb] = __builtin_amdgcn_mfma_f32_16x16x32_bf16(plo, vhi, oacc[cb], 0, 0, 0);
                oacc[cb] = __builtin_amdgcn_mfma_f32_16x16x32_bf16(phi, vlo, oacc[cb], 0, 0, 0);
                oacc[cb] = __builtin_amdgcn_mfma_f32_16x16x32_bf16(phi, vhi, oacc[cb], 0, 0, 0);
            }
        }
    }

#pragma unroll
    for (int reg = 0; reg < 4; reg++) {
        int gq = q0 + w*16 + quad*4 + reg;
        if (gq < T) {
            float inv = 1.0f / l_s[w*16 + quad*4 + reg];
#pragma unroll
            for (int cb = 0; cb < 4; cb++) {
                float v = oacc[cb][reg] * inv;
                unsigned short hh, ll;
                split_bf16(v, hh, ll);
                size_t o = (size_t)(b*T + gq)*384 + h*64 + cb*16 + l16;
                out_hi[o] = hh;
                out_lo[o] = ll;
            }
        }
    }
}

// ---------------- cls-row stats (reads split qkv planes) ----------------
__global__ __launch_bounds__(256) void cls_stats_kernel(const unsigned short* __restrict__ qh,
                                                        const unsigned short* __restrict__ ql,
                                                        float* __restrict__ raw_h,
                                                        float* __restrict__ ent,
                                                        const int* __restrict__ dT)
{
    int T = *dT;
    int bh = blockIdx.x;
    int b = bh / NHEADS, h = bh % NHEADS;
    __shared__ float q0s[64];
    __shared__ float logit[TMAXT];
    __shared__ float red[8];
    int t = threadIdx.x;
    if (t < 64) {
        size_t o = (size_t)(b*T)*1152 + h*64 + t;
        q0s[t] = bf16_to_f(qh[o]) + bf16_to_f(ql[o]);
    }
    __syncthreads();
    float lmax = -INFINITY;
    for (int j = t; j < T; j += 256) {
        size_t o = (size_t)(b*T + j)*1152 + 384 + h*64;
        float dot = 0.f;
#pragma unroll
        for (int d = 0; d < 64; d += 4) {
            ushort4 a = *(const ushort4*)(qh + o + d);
            ushort4 c = *(const ushort4*)(ql + o + d);
            dot += q0s[d+0]*(bf16_to_f(a.x)+bf16_to_f(c.x));
            dot += q0s[d+1]*(bf16_to_f(a.y)+bf16_to_f(c.y));
            dot += q0s[d+2]*(bf16_to_f(a.z)+bf16_to_f(c.z));
            dot += q0s[d+3]*(bf16_to_f(a.w)+bf16_to_f(c.w));
        }
        float lg = dot * 0.125f;
        logit[j] = lg;
        lmax = fmaxf(lmax, lg);
    }
#pragma unroll
    for (int off = 32; off; off >>= 1) lmax = fmaxf(lmax, __shfl_xor(lmax, off, 64));
    if ((t & 63) == 0) red[t >> 6] = lmax;
    __syncthreads();
    float gmax = fmaxf(fmaxf(red[0], red[1]), fmaxf(red[2], red[3]));
    __syncthreads();
    float psum = 0.f;
    for (int j = t; j < T; j += 256) psum += expf(logit[j] - gmax);
#pragma unroll
    for (int off = 32; off; off >>= 1) psum += __shfl_xor(psum, off, 64);
    if ((t & 63) == 0) red[4 + (t >> 6)] = psum;
    __syncthreads();
    float inv = 1.0f / (red[4] + red[5] + red[6] + red[7]);
    float entp = 0.f;
    for (int j = t; j < T; j += 256) {
        float p = expf(logit[j] - gmax) * inv;
        entp += -p * logf(p + 1e-6f);
        if (j >= 1) {
            size_t o = (size_t)(b*T + j)*1152 + 768 + h*64;
            float vn = 0.f;
#pragma unroll
            for (int d = 0; d < 64; d += 4) {
                ushort4 a = *(const ushort4*)(qh + o + d);
                ushort4 c = *(const ushort4*)(ql + o + d);
                float v0 = bf16_to_f(a.x)+bf16_to_f(c.x);
                float v1 = bf16_to_f(a.y)+bf16_to_f(c.y);
                float v2 = bf16_to_f(a.z)+bf16_to_f(c.z);
                float v3 = bf16_to_f(a.w)+bf16_to_f(c.w);
                vn += v0*v0 + v1*v1 + v2*v2 + v3*v3;
            }
            raw_h[(size_t)bh*576 + (j - 1)] = p * sqrtf(vn);
        }
    }
#pragma unroll
    for (int off = 32; off; off >>= 1) entp += __shfl_xor(entp, off, 64);
    __syncthreads();
    if ((t & 63) == 0) red[t >> 6] = entp;
    __syncthreads();
    if (t == 0) ent[bh] = red[0] + red[1] + red[2] + red[3];
}

// ---------------- prune decision v3: vectorized, register-resident rank ----------------
__global__ __launch_bounds__(256) void decide_kernel(const float* __restrict__ raw_h,
                                                     const float* __restrict__ ent,
                                                     float* __restrict__ prev_mass,
                                                     int* __restrict__ keep,
                                                     const int* __restrict__ dT,
                                                     int* __restrict__ dTnext,
                                                     int layer)
{
    int t = threadIdx.x;
    int T = *dT, N = T - 1;
    __shared__ __align__(16) float rbS[8][580];
    __shared__ float massS[8];
    __shared__ float pmS[8];
    __shared__ float esumS;
    __shared__ __align__(16) float scores[NMAXT];
    __shared__ int   keptFlag[NMAXT];
    __shared__ int   nnS;
    __shared__ int   wsum[4], wpre[4];

    if (N <= 16) {
        for (int i = t; i < T; i += 256) keep[i] = i;
        if (t == 0) *dTnext = T;
        return;
    }
    if (t < 8) pmS[t] = prev_mass[t];

    // phase A: rb[b][j] via float4 loads (independent, pipelined); masked mass partial
    {
        int b = t >> 5, lane = t & 31;
        const float* base = raw_h + (size_t)b * 6 * 576;
        float s = 0.f;
#pragma unroll
        for (int j0 = 0; j0 < 576; j0 += 128) {
            int j = j0 + lane * 4;
            if (j < 576) {
                float4 a0 = *(const float4*)(base + 0*576 + j);
                float4 a1 = *(const float4*)(base + 1*576 + j);
                float4 a2 = *(const float4*)(base + 2*576 + j);
                float4 a3 = *(const float4*)(base + 3*576 + j);
                float4 a4 = *(const float4*)(base + 4*576 + j);
                float4 a5 = *(const float4*)(base + 5*576 + j);
                float4 r;
                r.x = ((a0.x + a1.x) + (a2.x + a3.x)) + (a4.x + a5.x);
                r.y = ((a0.y + a1.y) + (a2.y + a3.y)) + (a4.y + a5.y);
                r.z = ((a0.z + a1.z) + (a2.z + a3.z)) + (a4.z + a5.z);
                r.w = ((a0.w + a1.w) + (a2.w + a3.w)) + (a4.w + a5.w);
                *(float4*)&rbS[b][j] = r;
                s += (j+0 < N ? r.x : 0.f) + (j+1 < N ? r.y : 0.f)
                   + (j+2 < N ? r.z : 0.f) + (j+3 < N ? r.w : 0.f);
            }
        }
#pragma unroll
        for (int off = 16; off; off >>= 1) s += __shfl_xor(s, off, 64);
        if (lane == 0) massS[b] = s;
    }
    if (t < 64) {
        float e = (t < 48) ? ent[t] : 0.f;
#pragma unroll
        for (int off = 32; off; off >>= 1) e += __shfl_xor(e, off, 64);
        if (t == 0) esumS = e;
    }
    __syncthreads();

    // phase C: scores[j] (division kept identical to passing version)
    for (int j = t; j < N; j += 256) {
        float s = 0.f;
#pragma unroll
        for (int b = 0; b < 8; b++)
            s += rbS[b][j] / (massS[b] + 1e-6f);
        scores[j] = s * 0.125f;
    }
    __syncthreads();

    if (t == 0) {
        float rho_mean = esumS / 48.0f / logf((float)T);
        int Nn;
        if (layer == 0) {
            Nn = N;
        } else {
            float dm = 0.f;
#pragma unroll
            for (int b = 0; b < 8; b++)
                dm += fabsf(massS[b] - pmS[b]) / (pmS[b] + 1e-6f);
            dm *= 0.125f;
            float kr = 1.0f - 0.1f * (rho_mean + dm);
            kr = fminf(fmaxf(kr, 0.0f), 1.0f);
            Nn = (int)((double)N * (double)kr);   // Python int() truncation
            if (Nn < 16) Nn = 16;
        }
        nnS = Nn;
        *dTnext = Nn + 1;
    }
    __syncthreads();
    if (t < 8) prev_mass[t] = massS[t];
    int Nn = nnS;

    if (Nn < N) {
        // phase D: rank — candidates in registers, one b128 sweep of scores
        float sj[3]; int jv[3]; int cnt[3];
#pragma unroll
        for (int q = 0; q < 3; q++) {
            int j = t + q * 256;
            jv[q] = (j < N) ? j : -1;
            sj[q] = (j < N) ? scores[j] : 0.f;
            cnt[q] = 0;
        }
        int nchunk = (N + 3) >> 2;
        for (int kk = 0; kk < nchunk; kk++) {
            float4 s4 = *(const float4*)&scores[kk * 4];
            int j2 = kk * 4;
#pragma unroll
            for (int e = 0; e < 4; e++) {
                float s2 = (e == 0) ? s4.x : (e == 1) ? s4.y : (e == 2) ? s4.z : s4.w;
                int jj = j2 + e;
                bool valid = jj < N;
#pragma unroll
                for (int q = 0; q < 3; q++)
                    cnt[q] += (valid && ((s2 > sj[q]) || (s2 == sj[q] && jj < jv[q]))) ? 1 : 0;
            }
        }
#pragma unroll
        for (int q = 0; q < 3; q++)
            if (jv[q] >= 0) keptFlag[jv[q]] = (cnt[q] < Nn) ? 1 : 0;
        __syncthreads();

        // phase E: parallel compaction (thread t owns j in [3t, 3t+3))
        int local = 0;
        int kf[3];
#pragma unroll
        for (int c = 0; c < 3; c++) {
            int j = 3*t + c;
            kf[c] = (j < N) ? keptFlag[j] : 0;
            local += kf[c];
        }
        int lane64 = t & 63, wv = t >> 6;
        int inc = local;
#pragma unroll
        for (int off = 1; off < 64; off <<= 1) {
            int nb = __shfl_up(inc, off, 64);
            if (lane64 >= off) inc += nb;
        }
        if (lane64 == 63) wsum[wv] = inc;
        __syncthreads();
        if (t == 0) {
            int run = 0;
#pragma unroll
            for (int i = 0; i < 4; i++) { wpre[i] = run; run += wsum[i]; }
            keep[0] = 0;
        }
        __syncthreads();
        int pos = 1 + (inc - local) + wpre[wv];
#pragma unroll
        for (int c = 0; c < 3; c++) {
            int j = 3*t + c;
            if (j < N && kf[c]) keep[pos++] = j + 1;
        }
    } else {
        for (int i = t; i < T; i += 256) keep[i] = i;
    }
}

// ---------------- gather pruned tokens (ping-pong) ----------------
__global__ __launch_bounds__(128) void gather_kernel(const float* __restrict__ src,
                                                     float* __restrict__ dst,
                                                     const int* __restrict__ keep,
                                                     const int* __restrict__ dT,
                                                     const int* __restrict__ dTnext)
{
    int Tn = *dTnext;
    int ti = blockIdx.x;
    if (ti >= Tn) return;
    int To = *dT;
    int b = blockIdx.y;
    const float* s = src + (size_t)(b*To + keep[ti]) * 384;
    float* d = dst + (size_t)(b*Tn + ti) * 384;
    int t = threadIdx.x;
    if (t < 96) ((float4*)d)[t] = ((const float4*)s)[t];
}

// ---------------- final LN on cls rows ----------------
__global__ __launch_bounds__(64) void lnf_kernel(const float* __restrict__ xin,
                                                 const float* __restrict__ sc,
                                                 const float* __restrict__ bi,
                                                 float* __restrict__ xf,
                                                 const int* __restrict__ dT)
{
    int T = *dT;
    int b = blockIdx.x;
    int lane = threadIdx.x;
    const float* xr = xin + (size_t)(b*T) * 384;
    float v[6];
#pragma unroll
    for (int i = 0; i < 6; i++) v[i] = xr[lane + 64*i];
    float s = v[0]+v[1]+v[2]+v[3]+v[4]+v[5];
#pragma unroll
    for (int off = 32; off; off >>= 1) s += __shfl_xor(s, off, 64);
    float mean = s * (1.0f/384.0f);
    float q = 0.f;
#pragma unroll
    for (int i = 0; i < 6; i++) { float d = v[i]-mean; q += d*d; }
#pragma unroll
    for (int off = 32; off; off >>= 1) q += __shfl_xor(q, off, 64);
    float rstd = 1.0f / sqrtf(q * (1.0f/384.0f) + 1e-5f);
#pragma unroll
    for (int i = 0; i < 6; i++) {
        int d = lane + 64*i;
        xf[(size_t)b*384 + d] = (v[i]-mean) * rstd * sc[d] + bi[d];
    }
}

// ---------------- head ----------------
__global__ __launch_bounds__(256) void head_kernel(const float* __restrict__ xf,
                                                   const float* __restrict__ hw,
                                                   const float* __restrict__ hb,
                                                   float* __restrict__ out)
{
    int idx = blockIdx.x * 256 + threadIdx.x;
    if (idx >= 8000) return;
    int b = idx / 1000, n = idx - b*1000;
    const float* xr = xf + (size_t)b*384;
    float s = hb[n];
#pragma unroll 4
    for (int k = 0; k < 384; k++) s += xr[k] * hw[(size_t)k*1000 + n];
    out[idx] = s;
}

// ---------------- launch ----------------
extern "C" void kernel_launch(void* const* d_in, const int* in_sizes, int n_in,
                              void* d_out, int out_size, void* d_ws, size_t ws_size,
                              hipStream_t stream)
{
    (void)in_sizes; (void)n_in; (void)out_size; (void)ws_size;
    const float* x       = (const float*)d_in[0];
    const float* patch_w = (const float*)d_in[1];
    const float* patch_b = (const float*)d_in[2];
    const float* cls_tok = (const float*)d_in[3];
    const float* pos     = (const float*)d_in[4];
    const float* ln1_s   = (const float*)d_in[5];
    const float* ln1_b   = (const float*)d_in[6];
    const float* qkv_w   = (const float*)d_in[7];
    const float* qkv_b   = (const float*)d_in[8];
    const float* proj_w  = (const float*)d_in[9];
    const float* proj_b  = (const float*)d_in[10];
    const float* ln2_s   = (const float*)d_in[11];
    const float* ln2_b   = (const float*)d_in[12];
    const float* fc1_w   = (const float*)d_in[13];
    const float* fc1_b   = (const float*)d_in[14];
    const float* fc2_w   = (const float*)d_in[15];
    const float* fc2_b   = (const float*)d_in[16];
    const float* norm_s  = (const float*)d_in[17];
    const float* norm_b  = (const float*)d_in[18];
    const float* head_w  = (const float*)d_in[19];
    const float* head_b  = (const float*)d_in[20];
    float* out = (float*)d_out;
    float* ws  = (float*)d_ws;

    float* x0   = ws + X0_OFF;
    float* x1   = ws + X1_OFF;
    float* rawh = ws + RAWH_OFF;
    float* entb = ws + ENT_OFF;
    float* pm   = ws + PM_OFF;
    float* xf   = ws + XF_OFF;
    int*   keep = (int*)(ws + KEEP_OFF);
    int*   dT0  = (int*)(ws + T_OFF);
    int*   dT1  = (int*)(ws + TN_OFF);

    unsigned short* xn_hi  = (unsigned short*)(ws + XN_OFF);
    unsigned short* xn_lo  = xn_hi + XSZ;
    unsigned short* qkv_hi = (unsigned short*)(ws + QKV_OFF);
    unsigned short* qkv_lo = qkv_hi + QKV_SZ;
    unsigned short* ao_hi  = (unsigned short*)(ws + AO_OFF);
    unsigned short* ao_lo  = ao_hi + XSZ;
    unsigned short* hb_hi  = (unsigned short*)(ws + QKV_OFF);   // aliases qkv (dead by fc1)
    unsigned short* hb_lo  = hb_hi + HBELEM;
    unsigned short* wspl   = (unsigned short*)(ws + WSPL_OFF);

    prologue_kernel<<<8, 128, 0, stream>>>(cls_tok, pos, x0, dT0);
    psplit_kernel<<<288, 256, 0, stream>>>(patch_w, wspl + W_PATCH, 768, 384);
    patch_mfma_kernel<<<dim3(6, 72), 256, 0, stream>>>(x, wspl + W_PATCH, patch_b, pos, x0);

    float* bufs[2] = { x0, x1 };
    for (int l = 0; l < LAYERS; l++) {
        float* src = bufs[l & 1];
        float* dst = bufs[(l + 1) & 1];
        int* cur = (l & 1) ? dT1 : dT0;
        int* nxt = (l & 1) ? dT0 : dT1;
        wsplit_kernel<<<dim3(576, 4), 256, 0, stream>>>(
            qkv_w + (size_t)l*384*1152, proj_w + (size_t)l*384*384,
            fc1_w + (size_t)l*384*1536, fc2_w + (size_t)l*1536*384, wspl);
        ln_kernel<<<1154, 256, 0, stream>>>(src, ln1_s + l*384, ln1_b + l*384, xn_hi, xn_lo, cur);
        gemm3_kernel<false><<<dim3(9, 73), 256, 0, stream>>>(
            xn_hi, xn_lo, wspl + W_QKV, qkv_b + l*1152, qkv_hi, qkv_lo, 384, 1152, cur);
        attn_kernel<<<dim3(10, 48), 256, 0, stream>>>(qkv_hi, qkv_lo, ao_hi, ao_lo, cur);
        cls_stats_kernel<<<48, 256, 0, stream>>>(qkv_hi, qkv_lo, rawh, entb, cur);
        gemm64_kernel<<<dim3(6, 73), 256, 0, stream>>>(
            ao_hi, ao_lo, wspl + W_PROJ, proj_b + l*384, src, src, 384, 384, cur);
        ln_kernel<<<1154, 256, 0, stream>>>(src, ln2_s + l*384, ln2_b + l*384, xn_hi, xn_lo, cur);
        gemm3_kernel<true><<<dim3(12, 73), 256, 0, stream>>>(
            xn_hi, xn_lo, wspl + W_FC1, fc1_b + l*1536, hb_hi, hb_lo, 384, 1536, cur);
        gemm64_kernel<<<dim3(6, 73), 256, 0, stream>>>(
            hb_hi, hb_lo, wspl + W_FC2, fc2_b + l*384, src, src, 1536, 384, cur);
        decide_kernel<<<1, 256, 0, stream>>>(rawh, entb, pm, keep, cur, nxt, l);
        gather_kernel<<<dim3(577, 8), 128, 0, stream>>>(src, dst, keep, cur, nxt);
    }
    lnf_kernel<<<8, 64, 0, stream>>>(bufs[0], norm_s, norm_b, xf, dT0);
    head_kernel<<<32, 256, 0, stream>>>(xf, head_w, head_b, out);
}

// Round 8
// 2345.189 us; speedup vs baseline: 1.1767x; 1.1767x over previous
//
#include <hip/hip_runtime.h>
#include <math.h>

#define NHEADS 6
#define DMODEL 384
#define TMAXT  577
#define NMAXT  576
#define BATCH  8
#define LAYERS 12

typedef __attribute__((ext_vector_type(8))) short bf16x8v;
typedef __attribute__((ext_vector_type(4))) float f32x4v;

// ---------------- workspace layout (float indices) ----------------
#define XSZ      (8ull*577*384)            // 1,772,544
#define X0_OFF   0ull
#define X1_OFF   (X0_OFF + XSZ)
#define XN_OFF   (X1_OFF + XSZ)            // xn split planes: 2 x XSZ ushort
#define QKV_OFF  (XN_OFF + XSZ)
#define QKV_SZ   (8ull*577*1152)           // elements per plane
#define AO_OFF   (QKV_OFF + QKV_SZ)        // qkv split planes = QKV_SZ floats total
#define HBELEM   (8ull*577*1536)
#define RAWH_OFF (AO_OFF + XSZ)
#define RAWH_SZ  (8ull*6*576)
#define ENT_OFF  (RAWH_OFF + RAWH_SZ)
#define PM_OFF   (ENT_OFF + 64)
#define XF_OFF   (PM_OFF + 64)
#define KEEP_OFF (XF_OFF + 8*384)
#define T_OFF    (KEEP_OFF + 640)          // T slot 0
#define TN_OFF   (T_OFF + 16)              // T slot 1
#define WSPL_OFF (TN_OFF + 16)

// weight split sub-offsets (ushort units inside WSPL)
#define W_QKV   0ull
#define W_PROJ  884736ull
#define W_FC1   1179648ull
#define W_FC2   2359296ull
#define W_PATCH 3538944ull                 // 768*384*2 = 589,824 ushorts

// scratch after WSPL (WSPL = 4,128,768 ushorts = 2,064,384 floats)
#define MASS_OFF  (WSPL_OFF + 2064384)
#define ESUM_OFF  (MASS_OFF + 16)
#define KFLAG_OFF (ESUM_OFF + 16)          // 640 ints

// ---------------- bf16 split helpers ----------------
__device__ inline unsigned short rne_bf16(float f) {
    unsigned int u = __float_as_uint(f);
    u += 0x7FFFu + ((u >> 16) & 1u);
    return (unsigned short)(u >> 16);
}
__device__ inline float bf16_to_f(unsigned short h) {
    return __uint_as_float(((unsigned int)h) << 16);
}
__device__ inline void split_bf16(float x, unsigned short& h, unsigned short& l) {
    h = rne_bf16(x);
    l = rne_bf16(x - bf16_to_f(h));
}

// shared Nn computation — identical fp expressions in drank and dfin (deterministic)
__device__ inline int compute_Nn(const float* __restrict__ massG,
                                 const float* __restrict__ pm,
                                 const float* __restrict__ esumG,
                                 int N, int T, int layer)
{
    if (layer == 0) return N;
    float rho_mean = (*esumG) / 48.0f / logf((float)T);
    float dm = 0.f;
#pragma unroll
    for (int b = 0; b < 8; b++)
        dm += fabsf(massG[b] - pm[b]) / (pm[b] + 1e-6f);
    dm *= 0.125f;
    float kr = 1.0f - 0.1f * (rho_mean + dm);
    kr = fminf(fmaxf(kr, 0.0f), 1.0f);
    int Nn = (int)((double)N * (double)kr);   // Python int() truncation
    if (Nn < 16) Nn = 16;
    return Nn;
}

// ---------------- prologue: cls row + pos, init T slot 0 ----------------
__global__ __launch_bounds__(128) void prologue_kernel(const float* __restrict__ cls_tok,
                                                       const float* __restrict__ pos,
                                                       float* __restrict__ x0,
                                                       int* __restrict__ dT0)
{
    int b = blockIdx.x;
    for (int d = threadIdx.x; d < 384; d += 128)
        x0[(size_t)b*577*384 + d] = cls_tok[d] + pos[d];
    if (b == 0 && threadIdx.x == 0) *dT0 = 577;
}

// ---------------- generic split+transpose: W[K][N] fp32 -> [N][K] hi/lo bf16 ----------------
__global__ __launch_bounds__(256) void psplit_kernel(const float* __restrict__ W,
                                                     unsigned short* __restrict__ dst,
                                                     int K, int N)
{
    int ktiles = K >> 5, ntiles = N >> 5;
    int tid = blockIdx.x;
    if (tid >= ktiles * ntiles) return;
    int tk = tid % ktiles, tn = tid / ktiles;
    int k0 = tk << 5, n0 = tn << 5;
    __shared__ unsigned short Th[32][34];
    __shared__ unsigned short Tl[32][34];
    int t = threadIdx.x;
    {
        int row = t >> 3, c4 = (t & 7) << 2;
        float4 wv = *(const float4*)(W + (size_t)(k0 + row) * N + n0 + c4);
        unsigned short h, l;
        split_bf16(wv.x, h, l); Th[c4+0][row] = h; Tl[c4+0][row] = l;
        split_bf16(wv.y, h, l); Th[c4+1][row] = h; Tl[c4+1][row] = l;
        split_bf16(wv.z, h, l); Th[c4+2][row] = h; Tl[c4+2][row] = l;
        split_bf16(wv.w, h, l); Th[c4+3][row] = h; Tl[c4+3][row] = l;
    }
    __syncthreads();
    {
        int n = t >> 3, k4 = (t & 7) << 2;
        unsigned short* dh = dst + (size_t)(n0 + n) * K + k0 + k4;
        unsigned short* dl = dh + (size_t)K * N;
        *(ushort4*)dh = make_ushort4(Th[n][k4], Th[n][k4+1], Th[n][k4+2], Th[n][k4+3]);
        *(ushort4*)dl = make_ushort4(Tl[n][k4], Tl[n][k4+1], Tl[n][k4+2], Tl[n][k4+3]);
    }
}

// ---------------- per-layer weight split (4 matrices) ----------------
__global__ __launch_bounds__(256) void wsplit_kernel(const float* __restrict__ qkvw,
                                                     const float* __restrict__ projw,
                                                     const float* __restrict__ fc1w,
                                                     const float* __restrict__ fc2w,
                                                     unsigned short* __restrict__ wspl)
{
    int mat = blockIdx.y;
    const float* W; int K, N; size_t off;
    if (mat == 0)      { W = qkvw; K = 384;  N = 1152; off = W_QKV; }
    else if (mat == 1) { W = projw; K = 384; N = 384;  off = W_PROJ; }
    else if (mat == 2) { W = fc1w; K = 384;  N = 1536; off = W_FC1; }
    else               { W = fc2w; K = 1536; N = 384;  off = W_FC2; }
    int ktiles = K >> 5, ntiles = N >> 5;
    int tid = blockIdx.x;
    if (tid >= ktiles * ntiles) return;
    int tk = tid % ktiles, tn = tid / ktiles;
    int k0 = tk << 5, n0 = tn << 5;
    __shared__ unsigned short Th[32][34];
    __shared__ unsigned short Tl[32][34];
    int t = threadIdx.x;
    {
        int row = t >> 3, c4 = (t & 7) << 2;
        float4 wv = *(const float4*)(W + (size_t)(k0 + row) * N + n0 + c4);
        unsigned short h, l;
        split_bf16(wv.x, h, l); Th[c4+0][row] = h; Tl[c4+0][row] = l;
        split_bf16(wv.y, h, l); Th[c4+1][row] = h; Tl[c4+1][row] = l;
        split_bf16(wv.z, h, l); Th[c4+2][row] = h; Tl[c4+2][row] = l;
        split_bf16(wv.w, h, l); Th[c4+3][row] = h; Tl[c4+3][row] = l;
    }
    __syncthreads();
    {
        int n = t >> 3, k4 = (t & 7) << 2;
        unsigned short* dh = wspl + off + (size_t)(n0 + n) * K + k0 + k4;
        unsigned short* dl = dh + (size_t)K * N;
        *(ushort4*)dh = make_ushort4(Th[n][k4], Th[n][k4+1], Th[n][k4+2], Th[n][k4+3]);
        *(ushort4*)dl = make_ushort4(Tl[n][k4], Tl[n][k4+1], Tl[n][k4+2], Tl[n][k4+3]);
    }
}

// ---------------- patch embed: bf16x3 MFMA, 64x64 tile ----------------
__global__ __launch_bounds__(256, 4) void patch_mfma_kernel(const float* __restrict__ x,
                                                            const unsigned short* __restrict__ Wt,
                                                            const float* __restrict__ pb,
                                                            const float* __restrict__ pos,
                                                            float* __restrict__ x0)
{
    const int K = 768, N = 384, M = 4608;
    int m0 = blockIdx.y * 64;
    int n0 = blockIdx.x * 64;

    __shared__ unsigned short As[2][64][40];
    __shared__ unsigned short Bs[2][64][40];

    int t = threadIdx.x;
    int lane = t & 63, w = t >> 6;
    int wr = w >> 1, wc = w & 1;
    int quad = lane >> 4, l16 = lane & 15;

    f32x4v acc[2][2];
#pragma unroll
    for (int i = 0; i < 2; i++)
#pragma unroll
        for (int j = 0; j < 2; j++) acc[i][j] = (f32x4v){0.f, 0.f, 0.f, 0.f};

    int arow = t >> 2, ak8 = (t & 3) * 8;
    int garow = m0 + arow;
    int ab = garow / 576, att = garow % 576;
    int g1 = att / 24, g2 = att % 24;
    const float* xr = x + ((size_t)(ab*3)*384 + g1*16)*384 + g2*16;

    int bn = t >> 2, bk8 = (t & 3) * 8;
    const unsigned short* Bh = Wt + (size_t)(n0 + bn) * K + bk8;
    const unsigned short* Bl = Bh + (size_t)K * N;

    for (int k0 = 0; k0 < K; k0 += 32) {
        int k = k0 + ak8;
        int c = k >> 8, rr = k & 255, p1 = rr >> 4, p2 = rr & 15;
        const float* src = xr + ((size_t)c*384 + p1)*384 + p2;
        float4 f0 = *(const float4*)(src);
        float4 f1 = *(const float4*)(src + 4);
        float f[8] = {f0.x, f0.y, f0.z, f0.w, f1.x, f1.y, f1.z, f1.w};
        unsigned short ah[8], al[8];
#pragma unroll
        for (int j = 0; j < 8; j++) split_bf16(f[j], ah[j], al[j]);
        uint4 vbh = *(const uint4*)(Bh + k0);
        uint4 vbl = *(const uint4*)(Bl + k0);
        __syncthreads();
        *(uint4*)&As[0][arow][ak8] = *(uint4*)ah;
        *(uint4*)&As[1][arow][ak8] = *(uint4*)al;
        *(uint4*)&Bs[0][bn][bk8] = vbh;
        *(uint4*)&Bs[1][bn][bk8] = vbl;
        __syncthreads();

        bf16x8v afh[2], afl[2], bfh[2], bfl[2];
#pragma unroll
        for (int rb = 0; rb < 2; rb++) {
            int r = wr * 32 + rb * 16 + l16;
            afh[rb] = *(const bf16x8v*)&As[0][r][quad * 8];
            afl[rb] = *(const bf16x8v*)&As[1][r][quad * 8];
        }
#pragma unroll
        for (int cb = 0; cb < 2; cb++) {
            int cc = wc * 32 + cb * 16 + l16;
            bfh[cb] = *(const bf16x8v*)&Bs[0][cc][quad * 8];
            bfl[cb] = *(const bf16x8v*)&Bs[1][cc][quad * 8];
        }
#pragma unroll
        for (int rb = 0; rb < 2; rb++)
#pragma unroll
            for (int cb = 0; cb < 2; cb++) {
                acc[rb][cb] = __builtin_amdgcn_mfma_f32_16x16x32_bf16(afl[rb], bfh[cb], acc[rb][cb], 0, 0, 0);
                acc[rb][cb] = __builtin_amdgcn_mfma_f32_16x16x32_bf16(afh[rb], bfl[cb], acc[rb][cb], 0, 0, 0);
                acc[rb][cb] = __builtin_amdgcn_mfma_f32_16x16x32_bf16(afh[rb], bfh[cb], acc[rb][cb], 0, 0, 0);
            }
    }

#pragma unroll
    for (int rb = 0; rb < 2; rb++) {
#pragma unroll
        for (int reg = 0; reg < 4; reg++) {
            int r = m0 + wr * 32 + rb * 16 + quad * 4 + reg;
            if (r >= M) continue;
            int bb = r / 576, ttt = r % 576;
#pragma unroll
            for (int cb = 0; cb < 2; cb++) {
                int cc = n0 + wc * 32 + cb * 16 + l16;
                float v = acc[rb][cb][reg] + pb[cc] + pos[(size_t)(1 + ttt)*384 + cc];
                x0[(size_t)(bb*577 + 1 + ttt)*384 + cc] = v;
            }
        }
    }
}

// ---------------- LayerNorm -> split bf16 planes ----------------
__global__ __launch_bounds__(256) void ln_kernel(const float* __restrict__ xin,
                                                 const float* __restrict__ sc,
                                                 const float* __restrict__ bi,
                                                 unsigned short* __restrict__ yhi,
                                                 unsigned short* __restrict__ ylo,
                                                 const int* __restrict__ dT)
{
    int T = *dT;
    int M = 8 * T;
    int r = blockIdx.x * 4 + (threadIdx.x >> 6);
    if (r >= M) return;
    int lane = threadIdx.x & 63;
    const float* xr = xin + (size_t)r * 384;
    float v[6];
#pragma unroll
    for (int i = 0; i < 6; i++) v[i] = xr[lane + 64*i];
    float s = v[0]+v[1]+v[2]+v[3]+v[4]+v[5];
#pragma unroll
    for (int off = 32; off; off >>= 1) s += __shfl_xor(s, off, 64);
    float mean = s * (1.0f/384.0f);
    float q = 0.f;
#pragma unroll
    for (int i = 0; i < 6; i++) { float d = v[i]-mean; q += d*d; }
#pragma unroll
    for (int off = 32; off; off >>= 1) q += __shfl_xor(q, off, 64);
    float rstd = 1.0f / sqrtf(q * (1.0f/384.0f) + 1e-5f);
#pragma unroll
    for (int i = 0; i < 6; i++) {
        int d = lane + 64*i;
        float y = (v[i]-mean) * rstd * sc[d] + bi[d];
        unsigned short h, l;
        split_bf16(y, h, l);
        yhi[(size_t)r*384 + d] = h;
        ylo[(size_t)r*384 + d] = l;
    }
}

// ---------------- bf16x3 MFMA GEMM, 64x128 tile, split-bf16 out (+optional gelu) ----------------
template<bool GELU>
__global__ __launch_bounds__(256, 3) void gemm3_kernel(const unsigned short* __restrict__ Ahi,
                                                       const unsigned short* __restrict__ Alo,
                                                       const unsigned short* __restrict__ Wt,
                                                       const float* __restrict__ bias,
                                                       unsigned short* __restrict__ Chi,
                                                       unsigned short* __restrict__ Clo,
                                                       int K, int N,
                                                       const int* __restrict__ dT)
{
    int T = *dT; int M = 8 * T;
    int m0 = blockIdx.y * 64;
    if (m0 >= M) return;
    int n0 = blockIdx.x * 128;

    __shared__ unsigned short As[2][64][40];
    __shared__ unsigned short Bs[2][128][40];

    int t = threadIdx.x;
    int lane = t & 63, w = t >> 6;
    int wr = w >> 1, wc = w & 1;
    int quad = lane >> 4, l16 = lane & 15;

    f32x4v acc[2][4];
#pragma unroll
    for (int i = 0; i < 2; i++)
#pragma unroll
        for (int j = 0; j < 4; j++) acc[i][j] = (f32x4v){0.f, 0.f, 0.f, 0.f};

    int arow = t >> 2, ak = (t & 3) * 8;
    int ag = m0 + arow; if (ag > M - 1) ag = M - 1;
    const unsigned short* Ah = Ahi + (size_t)ag * K + ak;
    const unsigned short* Al = Alo + (size_t)ag * K + ak;

    int bn = t >> 1, bk = (t & 1) * 16;
    const unsigned short* Bh = Wt + (size_t)(n0 + bn) * K + bk;
    const unsigned short* Bl = Bh + (size_t)K * N;

    for (int k0 = 0; k0 < K; k0 += 32) {
        uint4 vah  = *(const uint4*)(Ah + k0);
        uint4 val  = *(const uint4*)(Al + k0);
        uint4 vbh0 = *(const uint4*)(Bh + k0);
        uint4 vbh1 = *(const uint4*)(Bh + k0 + 8);
        uint4 vbl0 = *(const uint4*)(Bl + k0);
        uint4 vbl1 = *(const uint4*)(Bl + k0 + 8);
        __syncthreads();
        *(uint4*)&As[0][arow][ak] = vah;
        *(uint4*)&As[1][arow][ak] = val;
        *(uint4*)&Bs[0][bn][bk]     = vbh0;
        *(uint4*)&Bs[0][bn][bk + 8] = vbh1;
        *(uint4*)&Bs[1][bn][bk]     = vbl0;
        *(uint4*)&Bs[1][bn][bk + 8] = vbl1;
        __syncthreads();

        bf16x8v afh[2], afl[2], bfh[4], bfl[4];
#pragma unroll
        for (int rb = 0; rb < 2; rb++) {
            int r = wr * 32 + rb * 16 + l16;
            afh[rb] = *(const bf16x8v*)&As[0][r][quad * 8];
            afl[rb] = *(const bf16x8v*)&As[1][r][quad * 8];
        }
#pragma unroll
        for (int cb = 0; cb < 4; cb++) {
            int c = wc * 64 + cb * 16 + l16;
            bfh[cb] = *(const bf16x8v*)&Bs[0][c][quad * 8];
            bfl[cb] = *(const bf16x8v*)&Bs[1][c][quad * 8];
        }
#pragma unroll
        for (int rb = 0; rb < 2; rb++)
#pragma unroll
            for (int cb = 0; cb < 4; cb++) {
                acc[rb][cb] = __builtin_amdgcn_mfma_f32_16x16x32_bf16(afl[rb], bfh[cb], acc[rb][cb], 0, 0, 0);
                acc[rb][cb] = __builtin_amdgcn_mfma_f32_16x16x32_bf16(afh[rb], bfl[cb], acc[rb][cb], 0, 0, 0);
                acc[rb][cb] = __builtin_amdgcn_mfma_f32_16x16x32_bf16(afh[rb], bfh[cb], acc[rb][cb], 0, 0, 0);
            }
    }

#pragma unroll
    for (int rb = 0; rb < 2; rb++) {
#pragma unroll
        for (int reg = 0; reg < 4; reg++) {
            int r = m0 + wr * 32 + rb * 16 + quad * 4 + reg;
            if (r >= M) continue;
#pragma unroll
            for (int cb = 0; cb < 4; cb++) {
                int c = n0 + wc * 64 + cb * 16 + l16;
                float v = acc[rb][cb][reg] + bias[c];
                if (GELU) v = 0.5f * v * (1.0f + erff(v * 0.70710678118654752440f));
                unsigned short h, l;
                split_bf16(v, h, l);
                Chi[(size_t)r * N + c] = h;
                Clo[(size_t)r * N + c] = l;
            }
        }
    }
}

// ---------------- bf16x3 MFMA GEMM, 64x64 tile, +resid, fp32 out (N=384 GEMMs) ----------------
__global__ __launch_bounds__(256, 4) void gemm64_kernel(const unsigned short* __restrict__ Ahi,
                                                        const unsigned short* __restrict__ Alo,
                                                        const unsigned short* __restrict__ Wt,
                                                        const float* __restrict__ bias,
                                                        const float* __restrict__ resid,
                                                        float* __restrict__ Cf,
                                                        int K, int N,
                                                        const int* __restrict__ dT)
{
    int T = *dT; int M = 8 * T;
    int m0 = blockIdx.y * 64;
    if (m0 >= M) return;
    int n0 = blockIdx.x * 64;

    __shared__ unsigned short As[2][64][40];
    __shared__ unsigned short Bs[2][64][40];

    int t = threadIdx.x;
    int lane = t & 63, w = t >> 6;
    int wr = w >> 1, wc = w & 1;
    int quad = lane >> 4, l16 = lane & 15;

    f32x4v acc[2][2];
#pragma unroll
    for (int i = 0; i < 2; i++)
#pragma unroll
        for (int j = 0; j < 2; j++) acc[i][j] = (f32x4v){0.f, 0.f, 0.f, 0.f};

    int arow = t >> 2, ak = (t & 3) * 8;
    int ag = m0 + arow; if (ag > M - 1) ag = M - 1;
    const unsigned short* Ah = Ahi + (size_t)ag * K + ak;
    const unsigned short* Al = Alo + (size_t)ag * K + ak;

    int bn = t >> 2, bk = (t & 3) * 8;
    const unsigned short* Bh = Wt + (size_t)(n0 + bn) * K + bk;
    const unsigned short* Bl = Bh + (size_t)K * N;

    for (int k0 = 0; k0 < K; k0 += 32) {
        uint4 vah = *(const uint4*)(Ah + k0);
        uint4 val = *(const uint4*)(Al + k0);
        uint4 vbh = *(const uint4*)(Bh + k0);
        uint4 vbl = *(const uint4*)(Bl + k0);
        __syncthreads();
        *(uint4*)&As[0][arow][ak] = vah;
        *(uint4*)&As[1][arow][ak] = val;
        *(uint4*)&Bs[0][bn][bk] = vbh;
        *(uint4*)&Bs[1][bn][bk] = vbl;
        __syncthreads();

        bf16x8v afh[2], afl[2], bfh[2], bfl[2];
#pragma unroll
        for (int rb = 0; rb < 2; rb++) {
            int r = wr * 32 + rb * 16 + l16;
            afh[rb] = *(const bf16x8v*)&As[0][r][quad * 8];
            afl[rb] = *(const bf16x8v*)&As[1][r][quad * 8];
        }
#pragma unroll
        for (int cb = 0; cb < 2; cb++) {
            int c = wc * 32 + cb * 16 + l16;
            bfh[cb] = *(const bf16x8v*)&Bs[0][c][quad * 8];
            bfl[cb] = *(const bf16x8v*)&Bs[1][c][quad * 8];
        }
#pragma unroll
        for (int rb = 0; rb < 2; rb++)
#pragma unroll
            for (int cb = 0; cb < 2; cb++) {
                acc[rb][cb] = __builtin_amdgcn_mfma_f32_16x16x32_bf16(afl[rb], bfh[cb], acc[rb][cb], 0, 0, 0);
                acc[rb][cb] = __builtin_amdgcn_mfma_f32_16x16x32_bf16(afh[rb], bfl[cb], acc[rb][cb], 0, 0, 0);
                acc[rb][cb] = __builtin_amdgcn_mfma_f32_16x16x32_bf16(afh[rb], bfh[cb], acc[rb][cb], 0, 0, 0);
            }
    }

#pragma unroll
    for (int rb = 0; rb < 2; rb++) {
#pragma unroll
        for (int reg = 0; reg < 4; reg++) {
            int r = m0 + wr * 32 + rb * 16 + quad * 4 + reg;
            if (r >= M) continue;
#pragma unroll
            for (int cb = 0; cb < 2; cb++) {
                int c = n0 + wc * 32 + cb * 16 + l16;
                float v = acc[rb][cb][reg] + bias[c] + resid[(size_t)r * N + c];
                Cf[(size_t)r * N + c] = v;
            }
        }
    }
}

// ---------------- flash attention v4: pre-split qkv planes, MFMA QK^T/PV ----------------
__global__ __launch_bounds__(256, 3) void attn_kernel(const unsigned short* __restrict__ qh,
                                                      const unsigned short* __restrict__ ql,
                                                      unsigned short* __restrict__ out_hi,
                                                      unsigned short* __restrict__ out_lo,
                                                      const int* __restrict__ dT)
{
    int T = *dT;
    int q0 = blockIdx.x * 64;
    if (q0 >= T) return;
    int bh = blockIdx.y;
    int b = bh / NHEADS, h = bh % NHEADS;

    __shared__ unsigned short Ks[2][64][72];   // K tile [tok][d]; later P [q][ktok]
    __shared__ unsigned short Vt[2][64][72];   // V^T tile [d][tok]
    __shared__ float Ss[64][66];
    __shared__ float m_s[64], l_s[64], al_s[64];

    int t = threadIdx.x;
    int lane = t & 63, w = t >> 6;
    int l16 = lane & 15, quad = lane >> 4;

    const bf16x8v zf = (bf16x8v){0,0,0,0,0,0,0,0};
    bf16x8v qf[2][2];   // [kstep][hi/lo]
    {
        int gq = q0 + w * 16 + l16;
        bool valid = gq < T;
        size_t base = (size_t)(b * T + (valid ? gq : 0)) * 1152 + h * 64;
#pragma unroll
        for (int ks = 0; ks < 2; ks++) {
            int off = ks * 32 + quad * 8;
            qf[ks][0] = valid ? *(const bf16x8v*)(qh + base + off) : zf;
            qf[ks][1] = valid ? *(const bf16x8v*)(ql + base + off) : zf;
        }
    }
    if (t < 64) { m_s[t] = -INFINITY; l_s[t] = 0.f; }

    f32x4v oacc[4];
#pragma unroll
    for (int cb = 0; cb < 4; cb++) oacc[cb] = (f32x4v){0.f, 0.f, 0.f, 0.f};

    int ntiles = (T + 63) >> 6;
    for (int kt = 0; kt < ntiles; kt++) {
        int kbase = kt * 64;
        __syncthreads();

        // stage K direct (pre-split), V transposed
        {
            int gk = kbase + lane;
            int sd0 = w * 16;
            bool valid = gk < T;
            size_t base = (size_t)(b * T + (valid ? gk : 0)) * 1152 + 384 + h * 64 + sd0;
            const uint4 z4 = make_uint4(0,0,0,0);
            uint4 kh0 = valid ? *(const uint4*)(qh + base)     : z4;
            uint4 kh1 = valid ? *(const uint4*)(qh + base + 8) : z4;
            uint4 kl0 = valid ? *(const uint4*)(ql + base)     : z4;
            uint4 kl1 = valid ? *(const uint4*)(ql + base + 8) : z4;
            *(uint4*)&Ks[0][lane][sd0]     = kh0;
            *(uint4*)&Ks[0][lane][sd0 + 8] = kh1;
            *(uint4*)&Ks[1][lane][sd0]     = kl0;
            *(uint4*)&Ks[1][lane][sd0 + 8] = kl1;
            uint4 vh0 = valid ? *(const uint4*)(qh + base + 384)     : z4;
            uint4 vh1 = valid ? *(const uint4*)(qh + base + 384 + 8) : z4;
            uint4 vl0 = valid ? *(const uint4*)(ql + base + 384)     : z4;
            uint4 vl1 = valid ? *(const uint4*)(ql + base + 384 + 8) : z4;
            unsigned short th[16], tl[16];
            *(uint4*)&th[0] = vh0; *(uint4*)&th[8] = vh1;
            *(uint4*)&tl[0] = vl0; *(uint4*)&tl[8] = vl1;
#pragma unroll
            for (int i = 0; i < 16; i++) {
                Vt[0][sd0 + i][lane] = th[i];
                Vt[1][sd0 + i][lane] = tl[i];
            }
        }
        __syncthreads();

        // S = Q K^T
#pragma unroll
        for (int cb = 0; cb < 4; cb++) {
            f32x4v sacc = (f32x4v){0.f, 0.f, 0.f, 0.f};
#pragma unroll
            for (int ks = 0; ks < 2; ks++) {
                bf16x8v bhi = *(const bf16x8v*)&Ks[0][cb*16 + l16][ks*32 + quad*8];
                bf16x8v blo = *(const bf16x8v*)&Ks[1][cb*16 + l16][ks*32 + quad*8];
                sacc = __builtin_amdgcn_mfma_f32_16x16x32_bf16(qf[ks][1], bhi, sacc, 0, 0, 0);
                sacc = __builtin_amdgcn_mfma_f32_16x16x32_bf16(qf[ks][0], blo, sacc, 0, 0, 0);
                sacc = __builtin_amdgcn_mfma_f32_16x16x32_bf16(qf[ks][0], bhi, sacc, 0, 0, 0);
            }
            int col = cb*16 + l16;
            int gk = kbase + col;
#pragma unroll
            for (int reg = 0; reg < 4; reg++)
                Ss[w*16 + quad*4 + reg][col] = (gk < T) ? sacc[reg]*0.125f : -INFINITY;
        }
        __syncthreads();

        // online softmax; P split overwrites Ks
        {
            int rr = t >> 2, sub = t & 3;
            float mx = -INFINITY;
#pragma unroll
            for (int kk = 0; kk < 16; kk++) mx = fmaxf(mx, Ss[rr][sub*16 + kk]);
            mx = fmaxf(mx, __shfl_xor(mx, 1, 64));
            mx = fmaxf(mx, __shfl_xor(mx, 2, 64));
            float mold = m_s[rr];
            float newm = fmaxf(mold, mx);
            float ps = 0.f;
#pragma unroll
            for (int kk = 0; kk < 16; kk++) {
                float p = __expf(Ss[rr][sub*16 + kk] - newm);
                unsigned short hh, ll;
                split_bf16(p, hh, ll);
                Ks[0][rr][sub*16 + kk] = hh;
                Ks[1][rr][sub*16 + kk] = ll;
                ps += p;
            }
            ps += __shfl_xor(ps, 1, 64);
            ps += __shfl_xor(ps, 2, 64);
            if (sub == 0) {
                float alpha = __expf(mold - newm);
                l_s[rr] = l_s[rr]*alpha + ps;
                m_s[rr] = newm;
                al_s[rr] = alpha;
            }
        }
        __syncthreads();

        // O = alpha*O + P V
#pragma unroll
        for (int reg = 0; reg < 4; reg++) {
            float a = al_s[w*16 + quad*4 + reg];
#pragma unroll
            for (int cb = 0; cb < 4; cb++) oacc[cb][reg] *= a;
        }
#pragma unroll
        for (int ks = 0; ks < 2; ks++) {
            bf16x8v phi = *(const bf16x8v*)&Ks[0][w*16 + l16][ks*32 + quad*8];
            bf16x8v plo = *(const bf16x8v*)&Ks[1][w*16 + l16][ks*32 + quad*8];
#pragma unroll
            for (int cb = 0; cb < 4; cb++) {
                bf16x8v vhi = *(const bf16x8v*)&Vt[0][cb*16 + l16][ks*32 + quad*8];
                bf16x8v vlo = *(const bf16x8v*)&Vt[1][cb*16 + l16][ks*32 + quad*8];
                oacc[cb] = __builtin_amdgcn_mfma_f32_16x16x32_bf16(plo, vhi, oacc[cb], 0, 0, 0);
                oacc[cb] = __builtin_amdgcn_mfma_f32_16x16x32_bf16(phi, vlo, oacc[cb], 0, 0, 0);
                oacc[cb] = __builtin_amdgcn_mfma_f32_16x16x32_bf16(phi, vhi, oacc[cb], 0, 0, 0);
            }
        }
    }

#pragma unroll
    for (int reg = 0; reg < 4; reg++) {
        int gq = q0 + w*16 + quad*4 + reg;
        if (gq < T) {
            float inv = 1.0f / l_s[w*16 + quad*4 + reg];
#pragma unroll
            for (int cb = 0; cb < 4; cb++) {
                float v = oacc[cb][reg] * inv;
                unsigned short hh, ll;
                split_bf16(v, hh, ll);
                size_t o = (size_t)(b*T + gq)*384 + h*64 + cb*16 + l16;
                out_hi[o] = hh;
                out_lo[o] = ll;
            }
        }
    }
}

// ---------------- cls-row stats (reads split qkv planes) ----------------
__global__ __launch_bounds__(256) void cls_stats_kernel(const unsigned short* __restrict__ qh,
                                                        const unsigned short* __restrict__ ql,
                                                        float* __restrict__ raw_h,
                                                        float* __restrict__ ent,
                                                        const int* __restrict__ dT)
{
    int T = *dT;
    int bh = blockIdx.x;
    int b = bh / NHEADS, h = bh % NHEADS;
    __shared__ float q0s[64];
    __shared__ float logit[TMAXT];
    __shared__ float red[8];
    int t = threadIdx.x;
    if (t < 64) {
        size_t o = (size_t)(b*T)*1152 + h*64 + t;
        q0s[t] = bf16_to_f(qh[o]) + bf16_to_f(ql[o]);
    }
    __syncthreads();
    float lmax = -INFINITY;
    for (int j = t; j < T; j += 256) {
        size_t o = (size_t)(b*T + j)*1152 + 384 + h*64;
        float dot = 0.f;
#pragma unroll
        for (int d = 0; d < 64; d += 4) {
            ushort4 a = *(const ushort4*)(qh + o + d);
            ushort4 c = *(const ushort4*)(ql + o + d);
            dot += q0s[d+0]*(bf16_to_f(a.x)+bf16_to_f(c.x));
            dot += q0s[d+1]*(bf16_to_f(a.y)+bf16_to_f(c.y));
            dot += q0s[d+2]*(bf16_to_f(a.z)+bf16_to_f(c.z));
            dot += q0s[d+3]*(bf16_to_f(a.w)+bf16_to_f(c.w));
        }
        float lg = dot * 0.125f;
        logit[j] = lg;
        lmax = fmaxf(lmax, lg);
    }
#pragma unroll
    for (int off = 32; off; off >>= 1) lmax = fmaxf(lmax, __shfl_xor(lmax, off, 64));
    if ((t & 63) == 0) red[t >> 6] = lmax;
    __syncthreads();
    float gmax = fmaxf(fmaxf(red[0], red[1]), fmaxf(red[2], red[3]));
    __syncthreads();
    float psum = 0.f;
    for (int j = t; j < T; j += 256) psum += expf(logit[j] - gmax);
#pragma unroll
    for (int off = 32; off; off >>= 1) psum += __shfl_xor(psum, off, 64);
    if ((t & 63) == 0) red[4 + (t >> 6)] = psum;
    __syncthreads();
    float inv = 1.0f / (red[4] + red[5] + red[6] + red[7]);
    float entp = 0.f;
    for (int j = t; j < T; j += 256) {
        float p = expf(logit[j] - gmax) * inv;
        entp += -p * logf(p + 1e-6f);
        if (j >= 1) {
            size_t o = (size_t)(b*T + j)*1152 + 768 + h*64;
            float vn = 0.f;
#pragma unroll
            for (int d = 0; d < 64; d += 4) {
                ushort4 a = *(const ushort4*)(qh + o + d);
                ushort4 c = *(const ushort4*)(ql + o + d);
                float v0 = bf16_to_f(a.x)+bf16_to_f(c.x);
                float v1 = bf16_to_f(a.y)+bf16_to_f(c.y);
                float v2 = bf16_to_f(a.z)+bf16_to_f(c.z);
                float v3 = bf16_to_f(a.w)+bf16_to_f(c.w);
                vn += v0*v0 + v1*v1 + v2*v2 + v3*v3;
            }
            raw_h[(size_t)bh*576 + (j - 1)] = p * sqrtf(vn);
        }
    }
#pragma unroll
    for (int off = 32; off; off >>= 1) entp += __shfl_xor(entp, off, 64);
    __syncthreads();
    if ((t & 63) == 0) red[t >> 6] = entp;
    __syncthreads();
    if (t == 0) ent[bh] = red[0] + red[1] + red[2] + red[3];
}

// ---------------- decide stage 1: mass[b] (blocks 0-7) + entropy sum (block 8) ----------------
__global__ __launch_bounds__(256) void dmass_kernel(const float* __restrict__ raw_h,
                                                    const float* __restrict__ ent,
                                                    float* __restrict__ massG,
                                                    float* __restrict__ esumG,
                                                    const int* __restrict__ dT)
{
    int T = *dT, N = T - 1;
    if (N <= 16) return;
    int b = blockIdx.x;
    int t = threadIdx.x;
    if (b == 8) {
        if (t < 64) {
            float e = (t < 48) ? ent[t] : 0.f;
#pragma unroll
            for (int off = 32; off; off >>= 1) e += __shfl_xor(e, off, 64);
            if (t == 0) *esumG = e;
        }
        return;
    }
    __shared__ float red[4];
    const float* base = raw_h + (size_t)b * 6 * 576;
    float s = 0.f;
    for (int j = t; j < N; j += 256) {
        float a0 = base[0*576 + j];
        float a1 = base[1*576 + j];
        float a2 = base[2*576 + j];
        float a3 = base[3*576 + j];
        float a4 = base[4*576 + j];
        float a5 = base[5*576 + j];
        s += ((a0 + a1) + (a2 + a3)) + (a4 + a5);
    }
#pragma unroll
    for (int off = 32; off; off >>= 1) s += __shfl_xor(s, off, 64);
    if ((t & 63) == 0) red[t >> 6] = s;
    __syncthreads();
    if (t == 0) massG[b] = red[0] + red[1] + red[2] + red[3];
}

// ---------------- decide stage 2: rank (3 blocks; each rebuilds scores identically) ----------------
__global__ __launch_bounds__(256) void drank_kernel(const float* __restrict__ raw_h,
                                                    const float* __restrict__ massG,
                                                    const float* __restrict__ pm,
                                                    const float* __restrict__ esumG,
                                                    int* __restrict__ keptFlagG,
                                                    const int* __restrict__ dT,
                                                    int layer)
{
    int T = *dT, N = T - 1;
    if (N <= 16 || layer == 0) return;
    int Nn = compute_Nn(massG, pm, esumG, N, T, layer);
    if (Nn >= N) return;

    __shared__ float scores[NMAXT];
    int t = threadIdx.x;
    // all blocks compute identical scores (same fp expressions/inputs -> bit-identical)
    for (int j = t; j < N; j += 256) {
        float s = 0.f;
#pragma unroll
        for (int b = 0; b < 8; b++) {
            const float* base = raw_h + (size_t)b * 6 * 576;
            float a0 = base[0*576 + j];
            float a1 = base[1*576 + j];
            float a2 = base[2*576 + j];
            float a3 = base[3*576 + j];
            float a4 = base[4*576 + j];
            float a5 = base[5*576 + j];
            float rb = ((a0 + a1) + (a2 + a3)) + (a4 + a5);
            s += rb / (massG[b] + 1e-6f);
        }
        scores[j] = s * 0.125f;
    }
    __syncthreads();

    int j = blockIdx.x * 256 + t;
    if (j >= N) return;
    float sj = scores[j];
    int cnt = 0;
    int j2 = 0;
    for (; j2 + 8 <= N; j2 += 8) {           // proven R6 strip-8 pattern (8 loads in flight)
        float x0 = scores[j2+0], x1 = scores[j2+1];
        float x2 = scores[j2+2], x3 = scores[j2+3];
        float x4 = scores[j2+4], x5 = scores[j2+5];
        float x6 = scores[j2+6], x7 = scores[j2+7];
        cnt += (x0 > sj) || (x0 == sj && j2+0 < j);
        cnt += (x1 > sj) || (x1 == sj && j2+1 < j);
        cnt += (x2 > sj) || (x2 == sj && j2+2 < j);
        cnt += (x3 > sj) || (x3 == sj && j2+3 < j);
        cnt += (x4 > sj) || (x4 == sj && j2+4 < j);
        cnt += (x5 > sj) || (x5 == sj && j2+5 < j);
        cnt += (x6 > sj) || (x6 == sj && j2+6 < j);
        cnt += (x7 > sj) || (x7 == sj && j2+7 < j);
    }
    for (; j2 < N; j2++) {
        float s2 = scores[j2];
        cnt += (s2 > sj) || (s2 == sj && j2 < j);
    }
    keptFlagG[j] = (cnt < Nn) ? 1 : 0;
}

// ---------------- decide stage 3: Nn, dTnext, prev_mass update, compaction ----------------
__global__ __launch_bounds__(256) void dfin_kernel(const float* __restrict__ massG,
                                                   const float* __restrict__ esumG,
                                                   float* __restrict__ pm,
                                                   const int* __restrict__ keptFlagG,
                                                   int* __restrict__ keep,
                                                   const int* __restrict__ dT,
                                                   int* __restrict__ dTnext,
                                                   int layer)
{
    int t = threadIdx.x;
    int T = *dT, N = T - 1;
    if (N <= 16) {
        for (int i = t; i < T; i += 256) keep[i] = i;
        if (t == 0) *dTnext = T;
        return;
    }
    __shared__ int nnS;
    __shared__ int wsum[4], wpre[4];
    if (t == 0) {
        int Nn = compute_Nn(massG, pm, esumG, N, T, layer);
        nnS = Nn;
        *dTnext = Nn + 1;
    }
    __syncthreads();
    if (t < 8) pm[t] = massG[t];             // after Nn read pm
    int Nn = nnS;

    if (Nn < N) {
        int local = 0;
        int kf[3];
#pragma unroll
        for (int c = 0; c < 3; c++) {
            int j = 3*t + c;
            kf[c] = (j < N) ? keptFlagG[j] : 0;
            local += kf[c];
        }
        int lane64 = t & 63, wv = t >> 6;
        int inc = local;
#pragma unroll
        for (int off = 1; off < 64; off <<= 1) {
            int nb = __shfl_up(inc, off, 64);
            if (lane64 >= off) inc += nb;
        }
        if (lane64 == 63) wsum[wv] = inc;
        __syncthreads();
        if (t == 0) {
            int run = 0;
#pragma unroll
            for (int i = 0; i < 4; i++) { wpre[i] = run; run += wsum[i]; }
            keep[0] = 0;
        }
        __syncthreads();
        int pos = 1 + (inc - local) + wpre[wv];
#pragma unroll
        for (int c = 0; c < 3; c++) {
            int j = 3*t + c;
            if (j < N && kf[c]) keep[pos++] = j + 1;
        }
    } else {
        for (int i = t; i < T; i += 256) keep[i] = i;
    }
}

// ---------------- gather pruned tokens (ping-pong) ----------------
__global__ __launch_bounds__(128) void gather_kernel(const float* __restrict__ src,
                                                     float* __restrict__ dst,
                                                     const int* __restrict__ keep,
                                                     const int* __restrict__ dT,
                                                     const int* __restrict__ dTnext)
{
    int Tn = *dTnext;
    int ti = blockIdx.x;
    if (ti >= Tn) return;
    int To = *dT;
    int b = blockIdx.y;
    const float* s = src + (size_t)(b*To + keep[ti]) * 384;
    float* d = dst + (size_t)(b*Tn + ti) * 384;
    int t = threadIdx.x;
    if (t < 96) ((float4*)d)[t] = ((const float4*)s)[t];
}

// ---------------- final LN on cls rows ----------------
__global__ __launch_bounds__(64) void lnf_kernel(const float* __restrict__ xin,
                                                 const float* __restrict__ sc,
                                                 const float* __restrict__ bi,
                                                 float* __restrict__ xf,
                                                 const int* __restrict__ dT)
{
    int T = *dT;
    int b = blockIdx.x;
    int lane = threadIdx.x;
    const float* xr = xin + (size_t)(b*T) * 384;
    float v[6];
#pragma unroll
    for (int i = 0; i < 6; i++) v[i] = xr[lane + 64*i];
    float s = v[0]+v[1]+v[2]+v[3]+v[4]+v[5];
#pragma unroll
    for (int off = 32; off; off >>= 1) s += __shfl_xor(s, off, 64);
    float mean = s * (1.0f/384.0f);
    float q = 0.f;
#pragma unroll
    for (int i = 0; i < 6; i++) { float d = v[i]-mean; q += d*d; }
#pragma unroll
    for (int off = 32; off; off >>= 1) q += __shfl_xor(q, off, 64);
    float rstd = 1.0f / sqrtf(q * (1.0f/384.0f) + 1e-5f);
#pragma unroll
    for (int i = 0; i < 6; i++) {
        int d = lane + 64*i;
        xf[(size_t)b*384 + d] = (v[i]-mean) * rstd * sc[d] + bi[d];
    }
}

// ---------------- head ----------------
__global__ __launch_bounds__(256) void head_kernel(const float* __restrict__ xf,
                                                   const float* __restrict__ hw,
                                                   const float* __restrict__ hb,
                                                   float* __restrict__ out)
{
    int idx = blockIdx.x * 256 + threadIdx.x;
    if (idx >= 8000) return;
    int b = idx / 1000, n = idx - b*1000;
    const float* xr = xf + (size_t)b*384;
    float s = hb[n];
#pragma unroll 4
    for (int k = 0; k < 384; k++) s += xr[k] * hw[(size_t)k*1000 + n];
    out[idx] = s;
}

// ---------------- launch ----------------
extern "C" void kernel_launch(void* const* d_in, const int* in_sizes, int n_in,
                              void* d_out, int out_size, void* d_ws, size_t ws_size,
                              hipStream_t stream)
{
    (void)in_sizes; (void)n_in; (void)out_size; (void)ws_size;
    const float* x       = (const float*)d_in[0];
    const float* patch_w = (const float*)d_in[1];
    const float* patch_b = (const float*)d_in[2];
    const float* cls_tok = (const float*)d_in[3];
    const float* pos     = (const float*)d_in[4];
    const float* ln1_s   = (const float*)d_in[5];
    const float* ln1_b   = (const float*)d_in[6];
    const float* qkv_w   = (const float*)d_in[7];
    const float* qkv_b   = (const float*)d_in[8];
    const float* proj_w  = (const float*)d_in[9];
    const float* proj_b  = (const float*)d_in[10];
    const float* ln2_s   = (const float*)d_in[11];
    const float* ln2_b   = (const float*)d_in[12];
    const float* fc1_w   = (const float*)d_in[13];
    const float* fc1_b   = (const float*)d_in[14];
    const float* fc2_w   = (const float*)d_in[15];
    const float* fc2_b   = (const float*)d_in[16];
    const float* norm_s  = (const float*)d_in[17];
    const float* norm_b  = (const float*)d_in[18];
    const float* head_w  = (const float*)d_in[19];
    const float* head_b  = (const float*)d_in[20];
    float* out = (float*)d_out;
    float* ws  = (float*)d_ws;

    float* x0    = ws + X0_OFF;
    float* x1    = ws + X1_OFF;
    float* rawh  = ws + RAWH_OFF;
    float* entb  = ws + ENT_OFF;
    float* pm    = ws + PM_OFF;
    float* xf    = ws + XF_OFF;
    float* massG = ws + MASS_OFF;
    float* esumG = ws + ESUM_OFF;
    int*   kflag = (int*)(ws + KFLAG_OFF);
    int*   keep  = (int*)(ws + KEEP_OFF);
    int*   dT0   = (int*)(ws + T_OFF);
    int*   dT1   = (int*)(ws + TN_OFF);

    unsigned short* xn_hi  = (unsigned short*)(ws + XN_OFF);
    unsigned short* xn_lo  = xn_hi + XSZ;
    unsigned short* qkv_hi = (unsigned short*)(ws + QKV_OFF);
    unsigned short* qkv_lo = qkv_hi + QKV_SZ;
    unsigned short* ao_hi  = (unsigned short*)(ws + AO_OFF);
    unsigned short* ao_lo  = ao_hi + XSZ;
    unsigned short* hb_hi  = (unsigned short*)(ws + QKV_OFF);   // aliases qkv (dead by fc1)
    unsigned short* hb_lo  = hb_hi + HBELEM;
    unsigned short* wspl   = (unsigned short*)(ws + WSPL_OFF);

    prologue_kernel<<<8, 128, 0, stream>>>(cls_tok, pos, x0, dT0);
    psplit_kernel<<<288, 256, 0, stream>>>(patch_w, wspl + W_PATCH, 768, 384);
    patch_mfma_kernel<<<dim3(6, 72), 256, 0, stream>>>(x, wspl + W_PATCH, patch_b, pos, x0);

    float* bufs[2] = { x0, x1 };
    for (int l = 0; l < LAYERS; l++) {
        float* src = bufs[l & 1];
        float* dst = bufs[(l + 1) & 1];
        int* cur = (l & 1) ? dT1 : dT0;
        int* nxt = (l & 1) ? dT0 : dT1;
        wsplit_kernel<<<dim3(576, 4), 256, 0, stream>>>(
            qkv_w + (size_t)l*384*1152, proj_w + (size_t)l*384*384,
            fc1_w + (size_t)l*384*1536, fc2_w + (size_t)l*1536*384, wspl);
        ln_kernel<<<1154, 256, 0, stream>>>(src, ln1_s + l*384, ln1_b + l*384, xn_hi, xn_lo, cur);
        gemm3_kernel<false><<<dim3(9, 73), 256, 0, stream>>>(
            xn_hi, xn_lo, wspl + W_QKV, qkv_b + l*1152, qkv_hi, qkv_lo, 384, 1152, cur);
        attn_kernel<<<dim3(10, 48), 256, 0, stream>>>(qkv_hi, qkv_lo, ao_hi, ao_lo, cur);
        cls_stats_kernel<<<48, 256, 0, stream>>>(qkv_hi, qkv_lo, rawh, entb, cur);
        gemm64_kernel<<<dim3(6, 73), 256, 0, stream>>>(
            ao_hi, ao_lo, wspl + W_PROJ, proj_b + l*384, src, src, 384, 384, cur);
        ln_kernel<<<1154, 256, 0, stream>>>(src, ln2_s + l*384, ln2_b + l*384, xn_hi, xn_lo, cur);
        gemm3_kernel<true><<<dim3(12, 73), 256, 0, stream>>>(
            xn_hi, xn_lo, wspl + W_FC1, fc1_b + l*1536, hb_hi, hb_lo, 384, 1536, cur);
        gemm64_kernel<<<dim3(6, 73), 256, 0, stream>>>(
            hb_hi, hb_lo, wspl + W_FC2, fc2_b + l*384, src, src, 1536, 384, cur);
        dmass_kernel<<<9, 256, 0, stream>>>(rawh, entb, massG, esumG, cur);
        drank_kernel<<<3, 256, 0, stream>>>(rawh, massG, pm, esumG, kflag, cur, l);
        dfin_kernel<<<1, 256, 0, stream>>>(massG, esumG, pm, kflag, keep, cur, nxt, l);
        gather_kernel<<<dim3(577, 8), 128, 0, stream>>>(src, dst, keep, cur, nxt);
    }
    lnf_kernel<<<8, 64, 0, stream>>>(bufs[0], norm_s, norm_b, xf, dT0);
    head_kernel<<<32, 256, 0, stream>>>(xf, head_w, head_b, out);
}